// Round 7
// baseline (105.630 us; speedup 1.0000x reference)
//
#include <hip/hip_runtime.h>

// Problem constants
#define NDIM 471
#define MD   128
#define TD   16384
#define KSEL 50
#define CGIT 24
#define WN   472            // W column count: 471 qt columns + 1 extra RHS (t1 = Q w)

// ws float-offset layout
#define WS_PART   0                 // [256][471] column-sum partials
#define WS_G      120832            // [128][128] Gram
#define WS_T1     137216            // [128]  t1 = Q w
#define WS_W      137472            // [128][472] W = Ginv @ [Q | t1] (via CG)
#define WS_XBAR   197888            // [471]
#define WS_W2     198400            // [471]
#define WS_RW     198912            // [471]  Rw = R @ w
#define WS_R      199424            // [471][471] R = (alpha/N) Q^T Ginv Q

// SGPR broadcast: readlane with compile-time lane index -> v_readlane_b32 s,v,imm
static __device__ __forceinline__ float rdl(float v, int lane){
    return __int_as_float(__builtin_amdgcn_readlane(__float_as_int(v), lane));
}

// ---- Kernel 1: blocks 0..255 Gram; 256..511 colsum partials; 512 t1 = Q w ----
__global__ __launch_bounds__(512) void k_gram_colsum(const float* __restrict__ qt,
                                                     const float* __restrict__ x,
                                                     const float* __restrict__ wv,
                                                     float* __restrict__ ws){
    int lane = threadIdx.x & 63, wid = threadIdx.x >> 6;
    if (blockIdx.x < 256){
        float* G = ws + WS_G;
        int gw = blockIdx.x * 8 + wid;          // 0..2047 waves
        int i = gw >> 4, jb = gw & 15;
        float qi[8];
#pragma unroll
        for (int s = 0; s < 8; ++s){ int idx = lane + 64*s; qi[s] = (idx < NDIM) ? qt[i*NDIM + idx] : 0.f; }
#pragma unroll
        for (int t = 0; t < 8; ++t){
            int j = jb + 16*t;
            float acc = 0.f;
#pragma unroll
            for (int s = 0; s < 8; ++s){
                int idx = lane + 64*s;
                float qj = (idx < NDIM) ? qt[j*NDIM + idx] : 0.f;
                acc = fmaf(qi[s], qj, acc);
            }
#pragma unroll
            for (int d = 1; d < 64; d <<= 1) acc += __shfl_xor(acc, d);
            if (lane == 0) G[i*MD + j] = acc;
        }
    } else if (blockIdx.x < 512){
        int cb = blockIdx.x - 256;              // 0..255, rows cb*64..+64
        int col = threadIdx.x;
        if (col < NDIM){
            const float* xp = x + (size_t)cb*64*NDIM + col;
            float acc = 0.f;
#pragma unroll 4
            for (int r = 0; r < 64; ++r) acc += xp[(size_t)r*NDIM];
            ws[WS_PART + cb*NDIM + col] = acc;
        }
    } else {
        // t1[m] = sum_idx qt[m][idx] * w[idx]
        for (int m = wid; m < MD; m += 8){
            float acc = 0.f;
#pragma unroll
            for (int s = 0; s < 8; ++s){
                int idx = lane + 64*s;
                if (idx < NDIM) acc = fmaf(qt[m*NDIM + idx], wv[idx], acc);
            }
#pragma unroll
            for (int d = 1; d < 64; d <<= 1) acc += __shfl_xor(acc, d);
            if (lane == 0) ws[WS_T1 + m] = acc;
        }
    }
}

// ---- Kernel 2: blocks 0..117 CG, split-K G layout (32 floats/thread); 118..176 xbar ----
// Thread duality: matvec role (row = tid&127, seg = tid>>7 owns G[row][seg*32..+31]);
// state role (c = tid>>7, row = tid&127 owns CG state of RHS column bid*4+c).
__global__ __launch_bounds__(512) void k_cg_xbar(const float* __restrict__ qt, float* __restrict__ ws){
    int tid = threadIdx.x, lane = tid & 63, wid = tid >> 6;
    if (blockIdx.x < 118){
        __shared__ __align__(16) float rl[4][128];       // r vector per RHS column
        __shared__ float part[4][4][128];                // [seg][c][row] partial dots
        __shared__ float red2[8][2];
        int row = tid & 127, seg = tid >> 7;             // matvec role (seg uniform per wave)
        int c   = seg;                                   // state role shares the split
        int col = blockIdx.x*4 + c;                      // 0..471 (col 471 = t1 RHS)
        // G slice: 32 floats/thread -> one full copy of G per block, register-resident
        float Gseg[32];
        const float* Gp = ws + WS_G + row*MD + seg*32;
#pragma unroll
        for (int k4 = 0; k4 < 8; ++k4){
            float4 gv = *(const float4*)(Gp + 4*k4);
            Gseg[4*k4+0]=gv.x; Gseg[4*k4+1]=gv.y; Gseg[4*k4+2]=gv.z; Gseg[4*k4+3]=gv.w;
        }
        float bvv = (col < NDIM) ? qt[row*NDIM + col] : ws[WS_T1 + row];
        float xv = 0.f, rv = bvv, pv = 0.f, sv = 0.f, gam = 1.f, alf = 1.f;
        rl[c][row] = rv;
        for (int it = 0; it < CGIT; ++it){
            __syncthreads();                             // A: rl visible
            // partial dots for all 4 columns over this thread's k-slice
#pragma unroll
            for (int cc = 0; cc < 4; ++cc){
                float2 rch = *(const float2*)&rl[cc][seg*32 + 2*(lane & 15)];
                float pa = 0.f, pb = 0.f;
#pragma unroll
                for (int k = 0; k < 16; ++k){
                    pa = fmaf(Gseg[2*k+0], rdl(rch.x, k), pa);
                    pb = fmaf(Gseg[2*k+1], rdl(rch.y, k), pb);
                }
                part[seg][cc][row] = pa + pb;
            }
            __syncthreads();                             // B: part visible
            float y = ((part[0][c][row] + part[1][c][row]) +
                       (part[2][c][row] + part[3][c][row]));
            // fused dots: gamma' = (r,r), delta = (Gr, r)
            float t0 = rv*rv, t1 = y*rv;
#pragma unroll
            for (int d = 1; d < 64; d <<= 1){ t0 += __shfl_xor(t0, d); t1 += __shfl_xor(t1, d); }
            if (lane == 0){ red2[wid][0] = t0; red2[wid][1] = t1; }
            __syncthreads();                             // C: red2 visible
            float gp = red2[2*c][0] + red2[2*c+1][0];
            float dl = red2[2*c][1] + red2[2*c+1][1];
            float bet, anew;
            if (it == 0){ bet = 0.f; anew = gp / fmaxf(dl, 1e-30f); }
            else { bet = gp / fmaxf(gam, 1e-30f); anew = gp / fmaxf(dl - bet*gp/alf, 1e-30f); }
            pv = fmaf(bet, pv, rv);
            sv = fmaf(bet, sv, y);
            xv = fmaf(anew, pv, xv);
            rv = fmaf(-anew, sv, rv);
            gam = gp; alf = anew;
            rl[c][row] = rv;
        }
        ws[WS_W + row*WN + col] = xv;
    } else {
        // xbar finalize: 8 columns per block, 256 partial rows
        __shared__ float part[8][8];
        int b2 = blockIdx.x - 118;              // 0..58
        int cl = tid & 7, seg = tid >> 3;       // seg 0..63
        int col = b2*8 + cl;
        float acc = 0.f;
        if (col < NDIM){
#pragma unroll
            for (int q = 0; q < 4; ++q) acc += ws[WS_PART + (seg*4 + q)*NDIM + col];
        }
        acc += __shfl_xor(acc, 8);
        acc += __shfl_xor(acc, 16);
        acc += __shfl_xor(acc, 32);
        if (lane < 8) part[wid][lane] = acc;    // lane<8 => cl==lane
        __syncthreads();
        if (tid < 8){
            float t = 0.f;
#pragma unroll
            for (int w2 = 0; w2 < 8; ++w2) t += part[w2][tid];
            int c2 = b2*8 + tid;
            if (c2 < NDIM) ws[WS_XBAR + c2] = t * (1.0f / TD);
        }
    }
}

// ---- Kernel 3: blocks 0..117 W2; 118..588 R rows; 589 Rw = sc*Q^T t2 ----
__global__ __launch_bounds__(256) void k_w2_r(const float* __restrict__ qt, const float* __restrict__ lw,
                                              const float* __restrict__ lb, const float* __restrict__ alpha,
                                              float* __restrict__ ws){
    if (blockIdx.x < 118){
        int lane = threadIdx.x & 63, wid = threadIdx.x >> 6;
        int i = blockIdx.x*4 + wid;
        if (i < NDIM){
            float acc = 0.f;
#pragma unroll
            for (int s = 0; s < 8; ++s){
                int idx = lane + 64*s;
                if (idx < NDIM) acc = fmaf(lw[(size_t)i*NDIM + idx], ws[WS_XBAR + idx], acc);
            }
#pragma unroll
            for (int d = 1; d < 64; d <<= 1) acc += __shfl_xor(acc, d);
            if (lane == 0) ws[WS_W2 + i] = acc + lb[i];
        }
    } else if (blockIdx.x < 589){
        int i = blockIdx.x - 118;           // 0..470 : row i of R
        __shared__ __align__(16) float qc[MD];
        int tid = threadIdx.x, lane = tid & 63;
        if (tid < MD) qc[tid] = qt[tid*NDIM + i];
        __syncthreads();
        float4 qv = ((const float4*)qc)[lane & 31];
        float sc = alpha[0] / (float)NDIM;
        const float* Wp = ws + WS_W;
        int j0 = tid;
        int j1 = (tid + 256 < NDIM) ? tid + 256 : (NDIM - 1);   // clamp (guarded store)
        float a0=0.f, a1=0.f, a2=0.f, a3=0.f;
        float b0=0.f, b1=0.f, b2=0.f, b3=0.f;
#pragma unroll 8
        for (int c = 0; c < 32; ++c){
            float p0 = rdl(qv.x, c), p1 = rdl(qv.y, c), p2 = rdl(qv.z, c), p3 = rdl(qv.w, c);
            const float* W0 = Wp + (4*c+0)*WN;
            const float* W1 = Wp + (4*c+1)*WN;
            const float* W2 = Wp + (4*c+2)*WN;
            const float* W3 = Wp + (4*c+3)*WN;
            a0 = fmaf(p0, W0[j0], a0); b0 = fmaf(p0, W0[j1], b0);
            a1 = fmaf(p1, W1[j0], a1); b1 = fmaf(p1, W1[j1], b1);
            a2 = fmaf(p2, W2[j0], a2); b2 = fmaf(p2, W2[j1], b2);
            a3 = fmaf(p3, W3[j0], a3); b3 = fmaf(p3, W3[j1], b3);
        }
        if (j0 < NDIM) ws[WS_R + (size_t)i*NDIM + j0] = sc * ((a0+a1) + (a2+a3));
        if (tid + 256 < NDIM) ws[WS_R + (size_t)i*NDIM + tid + 256] = sc * ((b0+b1) + (b2+b3));
    } else {
        // Rw_i = sc * sum_k qt[k][i] * t2[k],  t2 = W[:,471] = Ginv (Q w)
        __shared__ float t2l[MD];
        int tid = threadIdx.x;
        if (tid < MD) t2l[tid] = ws[WS_W + tid*WN + 471];
        __syncthreads();
        float sc = alpha[0] / (float)NDIM;
        for (int i = tid; i < NDIM; i += 256){
            float a0=0.f, a1=0.f, a2=0.f, a3=0.f;
#pragma unroll
            for (int k = 0; k < MD; k += 4){
                a0 = fmaf(qt[(k+0)*NDIM + i], t2l[k+0], a0);
                a1 = fmaf(qt[(k+1)*NDIM + i], t2l[k+1], a1);
                a2 = fmaf(qt[(k+2)*NDIM + i], t2l[k+2], a2);
                a3 = fmaf(qt[(k+3)*NDIM + i], t2l[k+3], a3);
            }
            ws[WS_RW + i] = sc * ((a0+a1) + (a2+a3));
        }
    }
}

// ---- Kernel 4: the 10-iteration solver (single block; prefetched matvec) ----
__global__ __launch_bounds__(512, 2) void k_iter(const float* __restrict__ wv,
                                              const float* __restrict__ alpha, const float* __restrict__ lamda,
                                              const float* __restrict__ rho_p, const float* __restrict__ mu_p,
                                              const float* __restrict__ ws, float* __restrict__ out){
    int tid = threadIdx.x, lane = tid & 63, wid = tid >> 6;
    bool act = tid < NDIM;
    int ti = act ? tid : 0;                      // clamped index for always-valid loads
    float rho = rho_p[0], mu = mu_p[0], lam = lamda[0];
    float sc  = alpha[0] / (float)NDIM;
    float wi  = act ? wv[tid]         : 0.f;
    float W2i = act ? ws[WS_W2 + tid] : 0.f;
    float Rwi = act ? ws[WS_RW + tid] : 0.f;

    __shared__ __align__(16) unsigned bins[1024];   // 4 buffers x 256 bins
    __shared__ __align__(8) float2 spair[64];       // packed (idx_bits, weight) support list
    __shared__ float warr[8];
    __shared__ unsigned wcnt[8];

    bins[tid] = 0u; bins[tid + 512] = 0u;
    __syncthreads();

    float z = 0.f, u = 0.f, Ruv = 0.f, Rzv = 0.f, Sz = 0.f;
    for (int it = 0; it < 10; ++it){
        float Rv = Ruv - rho*(Rzv - Rwi);
        float b  = wi + Rv;
        float grad = W2i + rho*(z - b) + u + 2.f*lam*(Sz - 1.f);
        float zn = z - mu*grad;
        zn = (act && zn > 0.f) ? zn : 0.f;
        unsigned bits = __float_as_uint(zn);

        // radix select: 1 barrier/pass; per-pass private bin buffer; redundant per-wave scan
        unsigned prefix = 0, need = KSEL;
#pragma unroll
        for (int pass = 3; pass >= 0; --pass){
            int sh = pass*8;
            unsigned* bp = bins + ((3 - pass) << 8);
            bool av = (pass == 3) || ((bits >> (sh + 8)) == (prefix >> (sh + 8)));
            if (av) atomicAdd(&bp[(bits >> sh) & 255u], 1u);
            __syncthreads();
            int base = 255 - 4*lane;
            uint4 bq = *(const uint4*)&bp[base - 3];
            unsigned b3 = bq.x, b2 = bq.y, b1 = bq.z, b0 = bq.w;   // b0 = bp[base] (highest)
            unsigned csum = b0 + b1 + b2 + b3;
            unsigned incl = csum;
#pragma unroll
            for (int d = 1; d < 64; d <<= 1){ unsigned t = __shfl_up(incl, d); if (lane >= d) incl += t; }
            unsigned excl = incl - csum;
            bool hit = (excl < need) && (need <= incl);
            unsigned long long hm = __ballot(hit);
            int hl = __ffsll((long long)hm) - 1;
            unsigned c0 = excl + b0, c1 = c0 + b1, c2 = c1 + b2;
            int byte; unsigned above;
            if      (need <= c0){ byte = base;   above = excl; }
            else if (need <= c1){ byte = base-1; above = c0; }
            else if (need <= c2){ byte = base-2; above = c1; }
            else                { byte = base-3; above = c2; }
            byte  = __shfl(byte, hl);
            above = (unsigned)__shfl((int)above, hl);
            prefix |= ((unsigned)byte) << sh;
            need -= above;
        }
        z = (act && bits >= prefix) ? zn : 0.f;

        // Sz + support list
        bool flag = z > 0.f;
        unsigned long long mb = __ballot(flag);
        float v = z;
#pragma unroll
        for (int d = 1; d < 64; d <<= 1) v += __shfl_xor(v, d);
        if (lane == 0){ warr[wid] = v; wcnt[wid] = (unsigned)__popcll(mb); }
        __syncthreads();
        Sz = ((warr[0]+warr[1])+(warr[2]+warr[3])) + ((warr[4]+warr[5])+(warr[6]+warr[7]));

        if (it < 9){
            unsigned off = 0;
#pragma unroll
            for (int w2 = 0; w2 < 8; ++w2) if (w2 < wid) off += wcnt[w2];
            off += (unsigned)__popcll(mb & ((1ull << lane) - 1ull));
            int cnt = 0;
#pragma unroll
            for (int w2 = 0; w2 < 8; ++w2) cnt += (int)wcnt[w2];
            if (flag){ spair[off] = make_float2(__int_as_float(tid), z); }
            if (tid >= cnt && tid < 64){ spair[tid] = make_float2(__int_as_float(0), 0.f); }  // exact pad
            bins[tid] = 0u; bins[tid + 512] = 0u;   // re-zero for next iteration
            __syncthreads();

            // one ds_read_b64/thread; (idx,weight) broadcast via readlane imm -> SGPR
            float2 pp = spair[lane];
            const float* Rb = ws + WS_R;
            // phase 1: issue all 56 loads (SGPR row base + coalesced tid offset)
            float rvv[56];
#pragma unroll
            for (int s = 0; s < 56; ++s){
                int j = __float_as_int(rdl(pp.x, s));
                rvv[s] = Rb[(size_t)j*NDIM + ti];
            }
            // phase 2: accumulate with SGPR weights, 4 chains
            float a0=0.f, a1=0.f, a2=0.f, a3=0.f;
#pragma unroll
            for (int s = 0; s < 56; s += 4){
                a0 = fmaf(rvv[s+0], rdl(pp.y, s+0), a0);
                a1 = fmaf(rvv[s+1], rdl(pp.y, s+1), a1);
                a2 = fmaf(rvv[s+2], rdl(pp.y, s+2), a2);
                a3 = fmaf(rvv[s+3], rdl(pp.y, s+3), a3);
            }
            float acc = (a0+a1) + (a2+a3);
            float Rbv = Rwi + sc*Rv;                // R@b = Rw + (alpha/N)*Rv   (P^2 = P)
            u   += rho*(z - b);
            Ruv += rho*(acc - Rbv);
            Rzv  = acc;
        }
    }
    if (act) out[tid] = z / (Sz + 1e-8f);
}

extern "C" void kernel_launch(void* const* d_in, const int* in_sizes, int n_in,
                              void* d_out, int out_size, void* d_ws, size_t ws_size,
                              hipStream_t stream) {
    const float* x     = (const float*)d_in[0];
    const float* qt    = (const float*)d_in[1];
    const float* wv    = (const float*)d_in[2];
    // d_in[3] = b1 (unused by forward math)
    const float* alpha = (const float*)d_in[4];
    const float* lamda = (const float*)d_in[5];
    const float* rho   = (const float*)d_in[6];
    const float* mu    = (const float*)d_in[7];
    const float* lw    = (const float*)d_in[8];
    const float* lb    = (const float*)d_in[9];
    float* out = (float*)d_out;
    float* ws  = (float*)d_ws;

    k_gram_colsum<<<513, 512, 0, stream>>>(qt, x, wv, ws);
    k_cg_xbar    <<<177, 512, 0, stream>>>(qt, ws);
    k_w2_r       <<<590, 256, 0, stream>>>(qt, lw, lb, alpha, ws);
    k_iter       <<<1,   512, 0, stream>>>(wv, alpha, lamda, rho, mu, ws, out);
}

// Round 8
// 99.236 us; speedup vs baseline: 1.0644x; 1.0644x over previous
//
#include <hip/hip_runtime.h>

// Problem constants
#define NDIM 471
#define MD   128
#define TD   16384
#define KSEL 50
#define CGIT 20
#define WN   472            // W column count: 471 qt columns + 1 extra RHS (t1 = Q w)

// ws float-offset layout
#define WS_PART   0                 // [256][471] column-sum partials
#define WS_G      120832            // [128][128] Gram
#define WS_T1     137216            // [128]  t1 = Q w
#define WS_W      137472            // [128][472] W = Ginv @ [Q | t1] (via CG)
#define WS_XBAR   197888            // [471]
#define WS_W2     198400            // [471]
#define WS_RW     198912            // [471]  Rw = R @ w
#define WS_R      199424            // [471][471] R = (alpha/N) Q^T Ginv Q

// SGPR broadcast: readlane with compile-time lane index -> v_readlane_b32 s,v,imm
static __device__ __forceinline__ float rdl(float v, int lane){
    return __int_as_float(__builtin_amdgcn_readlane(__float_as_int(v), lane));
}

// ---- Kernel 1: blocks 0..255 Gram; 256..511 colsum partials; 512 t1 = Q w ----
__global__ __launch_bounds__(512) void k_gram_colsum(const float* __restrict__ qt,
                                                     const float* __restrict__ x,
                                                     const float* __restrict__ wv,
                                                     float* __restrict__ ws){
    int lane = threadIdx.x & 63, wid = threadIdx.x >> 6;
    if (blockIdx.x < 256){
        float* G = ws + WS_G;
        int gw = blockIdx.x * 8 + wid;          // 0..2047 waves
        int i = gw >> 4, jb = gw & 15;
        float qi[8];
#pragma unroll
        for (int s = 0; s < 8; ++s){ int idx = lane + 64*s; qi[s] = (idx < NDIM) ? qt[i*NDIM + idx] : 0.f; }
#pragma unroll
        for (int t = 0; t < 8; ++t){
            int j = jb + 16*t;
            float acc = 0.f;
#pragma unroll
            for (int s = 0; s < 8; ++s){
                int idx = lane + 64*s;
                float qj = (idx < NDIM) ? qt[j*NDIM + idx] : 0.f;
                acc = fmaf(qi[s], qj, acc);
            }
#pragma unroll
            for (int d = 1; d < 64; d <<= 1) acc += __shfl_xor(acc, d);
            if (lane == 0) G[i*MD + j] = acc;
        }
    } else if (blockIdx.x < 512){
        int cb = blockIdx.x - 256;              // 0..255, rows cb*64..+64
        int col = threadIdx.x;
        if (col < NDIM){
            const float* xp = x + (size_t)cb*64*NDIM + col;
            float acc = 0.f;
#pragma unroll 4
            for (int r = 0; r < 64; ++r) acc += xp[(size_t)r*NDIM];
            ws[WS_PART + cb*NDIM + col] = acc;
        }
    } else {
        // t1[m] = sum_idx qt[m][idx] * w[idx]
        for (int m = wid; m < MD; m += 8){
            float acc = 0.f;
#pragma unroll
            for (int s = 0; s < 8; ++s){
                int idx = lane + 64*s;
                if (idx < NDIM) acc = fmaf(qt[m*NDIM + idx], wv[idx], acc);
            }
#pragma unroll
            for (int d = 1; d < 64; d <<= 1) acc += __shfl_xor(acc, d);
            if (lane == 0) ws[WS_T1 + m] = acc;
        }
    }
}

// ---- Kernel 2: blocks 0..117 CG, split-K, G slice in 32 NAMED scalar registers ----
// Thread (row = tid&127, seg = tid>>7) holds G[row][seg*32..+31]; same thread's CG
// state role is (c = seg, row). Named scalars (no arrays) force SROA -> true VGPRs.
// (R5-R7 counters: VGPR_Count 80/80/32 -> array slices went to scratch/refetch.)
#define G_LD(n) float4 t##n = *(const float4*)(Gp + 4*(n)); \
                float Ga##n = t##n.x, Gb##n = t##n.y, Gc##n = t##n.z, Gd##n = t##n.w;
#define G_DOT(n) pa = fmaf(Ga##n, rdl(rch.x, 2*(n)),   pa); \
                 pb = fmaf(Gb##n, rdl(rch.y, 2*(n)),   pb); \
                 pa = fmaf(Gc##n, rdl(rch.x, 2*(n)+1), pa); \
                 pb = fmaf(Gd##n, rdl(rch.y, 2*(n)+1), pb);

__global__ __launch_bounds__(512, 2) void k_cg_xbar(const float* __restrict__ qt, float* __restrict__ ws){
    int tid = threadIdx.x, lane = tid & 63, wid = tid >> 6;
    if (blockIdx.x < 118){
        __shared__ __align__(16) float rl[4][128];       // r vector per RHS column
        __shared__ float part[4][4][128];                // [seg][c][row] partial dots
        __shared__ float red2[8][2];
        int row = tid & 127, seg = tid >> 7;             // seg uniform per wave
        int c   = seg;                                   // state role shares the split
        int col = blockIdx.x*4 + c;                      // 0..471 (col 471 = t1 RHS)
        const float* Gp = ws + WS_G + row*MD + seg*32;
        G_LD(0) G_LD(1) G_LD(2) G_LD(3) G_LD(4) G_LD(5) G_LD(6) G_LD(7)
        float bvv = (col < NDIM) ? qt[row*NDIM + col] : ws[WS_T1 + row];
        float xv = 0.f, rv = bvv, pv = 0.f, sv = 0.f, gam = 1.f, alf = 1.f;
        rl[c][row] = rv;
        for (int it = 0; it < CGIT; ++it){
            __syncthreads();                             // A: rl visible
            // partial dots for all 4 columns over this thread's k-slice
#pragma unroll
            for (int cc = 0; cc < 4; ++cc){
                float2 rch = *(const float2*)&rl[cc][seg*32 + 2*(lane & 15)];
                float pa = 0.f, pb = 0.f;
                G_DOT(0) G_DOT(1) G_DOT(2) G_DOT(3) G_DOT(4) G_DOT(5) G_DOT(6) G_DOT(7)
                part[seg][cc][row] = pa + pb;
            }
            __syncthreads();                             // B: part visible
            float y = ((part[0][c][row] + part[1][c][row]) +
                       (part[2][c][row] + part[3][c][row]));
            // fused dots: gamma' = (r,r), delta = (Gr, r)
            float t0 = rv*rv, t1 = y*rv;
#pragma unroll
            for (int d = 1; d < 64; d <<= 1){ t0 += __shfl_xor(t0, d); t1 += __shfl_xor(t1, d); }
            if (lane == 0){ red2[wid][0] = t0; red2[wid][1] = t1; }
            __syncthreads();                             // C: red2 visible
            float gp = red2[2*c][0] + red2[2*c+1][0];
            float dl = red2[2*c][1] + red2[2*c+1][1];
            float bet, anew;
            if (it == 0){ bet = 0.f; anew = gp / fmaxf(dl, 1e-30f); }
            else { bet = gp / fmaxf(gam, 1e-30f); anew = gp / fmaxf(dl - bet*gp/alf, 1e-30f); }
            pv = fmaf(bet, pv, rv);
            sv = fmaf(bet, sv, y);
            xv = fmaf(anew, pv, xv);
            rv = fmaf(-anew, sv, rv);
            gam = gp; alf = anew;
            rl[c][row] = rv;
        }
        ws[WS_W + row*WN + col] = xv;
    } else {
        // xbar finalize: 8 columns per block, 256 partial rows
        __shared__ float part[8][8];
        int b2 = blockIdx.x - 118;              // 0..58
        int cl = tid & 7, seg = tid >> 3;       // seg 0..63
        int col = b2*8 + cl;
        float acc = 0.f;
        if (col < NDIM){
#pragma unroll
            for (int q = 0; q < 4; ++q) acc += ws[WS_PART + (seg*4 + q)*NDIM + col];
        }
        acc += __shfl_xor(acc, 8);
        acc += __shfl_xor(acc, 16);
        acc += __shfl_xor(acc, 32);
        if (lane < 8) part[wid][lane] = acc;    // lane<8 => cl==lane
        __syncthreads();
        if (tid < 8){
            float t = 0.f;
#pragma unroll
            for (int w2 = 0; w2 < 8; ++w2) t += part[w2][tid];
            int c2 = b2*8 + tid;
            if (c2 < NDIM) ws[WS_XBAR + c2] = t * (1.0f / TD);
        }
    }
}

// ---- Kernel 3: blocks 0..117 W2; 118..588 R rows; 589 Rw = sc*Q^T t2 ----
__global__ __launch_bounds__(256) void k_w2_r(const float* __restrict__ qt, const float* __restrict__ lw,
                                              const float* __restrict__ lb, const float* __restrict__ alpha,
                                              float* __restrict__ ws){
    if (blockIdx.x < 118){
        int lane = threadIdx.x & 63, wid = threadIdx.x >> 6;
        int i = blockIdx.x*4 + wid;
        if (i < NDIM){
            float acc = 0.f;
#pragma unroll
            for (int s = 0; s < 8; ++s){
                int idx = lane + 64*s;
                if (idx < NDIM) acc = fmaf(lw[(size_t)i*NDIM + idx], ws[WS_XBAR + idx], acc);
            }
#pragma unroll
            for (int d = 1; d < 64; d <<= 1) acc += __shfl_xor(acc, d);
            if (lane == 0) ws[WS_W2 + i] = acc + lb[i];
        }
    } else if (blockIdx.x < 589){
        int i = blockIdx.x - 118;           // 0..470 : row i of R
        __shared__ __align__(16) float qc[MD];
        int tid = threadIdx.x, lane = tid & 63;
        if (tid < MD) qc[tid] = qt[tid*NDIM + i];
        __syncthreads();
        float4 qv = ((const float4*)qc)[lane & 31];
        float sc = alpha[0] / (float)NDIM;
        const float* Wp = ws + WS_W;
        int j0 = tid;
        int j1 = (tid + 256 < NDIM) ? tid + 256 : (NDIM - 1);   // clamp (guarded store)
        float a0=0.f, a1=0.f, a2=0.f, a3=0.f;
        float b0=0.f, b1=0.f, b2=0.f, b3=0.f;
#pragma unroll 8
        for (int c = 0; c < 32; ++c){
            float p0 = rdl(qv.x, c), p1 = rdl(qv.y, c), p2 = rdl(qv.z, c), p3 = rdl(qv.w, c);
            const float* W0 = Wp + (4*c+0)*WN;
            const float* W1 = Wp + (4*c+1)*WN;
            const float* W2 = Wp + (4*c+2)*WN;
            const float* W3 = Wp + (4*c+3)*WN;
            a0 = fmaf(p0, W0[j0], a0); b0 = fmaf(p0, W0[j1], b0);
            a1 = fmaf(p1, W1[j0], a1); b1 = fmaf(p1, W1[j1], b1);
            a2 = fmaf(p2, W2[j0], a2); b2 = fmaf(p2, W2[j1], b2);
            a3 = fmaf(p3, W3[j0], a3); b3 = fmaf(p3, W3[j1], b3);
        }
        if (j0 < NDIM) ws[WS_R + (size_t)i*NDIM + j0] = sc * ((a0+a1) + (a2+a3));
        if (tid + 256 < NDIM) ws[WS_R + (size_t)i*NDIM + tid + 256] = sc * ((b0+b1) + (b2+b3));
    } else {
        // Rw_i = sc * sum_k qt[k][i] * t2[k],  t2 = W[:,471] = Ginv (Q w)
        __shared__ float t2l[MD];
        int tid = threadIdx.x;
        if (tid < MD) t2l[tid] = ws[WS_W + tid*WN + 471];
        __syncthreads();
        float sc = alpha[0] / (float)NDIM;
        for (int i = tid; i < NDIM; i += 256){
            float a0=0.f, a1=0.f, a2=0.f, a3=0.f;
#pragma unroll
            for (int k = 0; k < MD; k += 4){
                a0 = fmaf(qt[(k+0)*NDIM + i], t2l[k+0], a0);
                a1 = fmaf(qt[(k+1)*NDIM + i], t2l[k+1], a1);
                a2 = fmaf(qt[(k+2)*NDIM + i], t2l[k+2], a2);
                a3 = fmaf(qt[(k+3)*NDIM + i], t2l[k+3], a3);
            }
            ws[WS_RW + i] = sc * ((a0+a1) + (a2+a3));
        }
    }
}

// ---- Kernel 4: the 10-iteration solver (single block; prefetched matvec) ----
__global__ __launch_bounds__(512, 2) void k_iter(const float* __restrict__ wv,
                                              const float* __restrict__ alpha, const float* __restrict__ lamda,
                                              const float* __restrict__ rho_p, const float* __restrict__ mu_p,
                                              const float* __restrict__ ws, float* __restrict__ out){
    int tid = threadIdx.x, lane = tid & 63, wid = tid >> 6;
    bool act = tid < NDIM;
    int ti = act ? tid : 0;                      // clamped index for always-valid loads
    float rho = rho_p[0], mu = mu_p[0], lam = lamda[0];
    float sc  = alpha[0] / (float)NDIM;
    float wi  = act ? wv[tid]         : 0.f;
    float W2i = act ? ws[WS_W2 + tid] : 0.f;
    float Rwi = act ? ws[WS_RW + tid] : 0.f;

    __shared__ __align__(16) unsigned bins[1024];   // 4 buffers x 256 bins
    __shared__ __align__(8) float2 spair[64];       // packed (idx_bits, weight) support list
    __shared__ float warr[8];
    __shared__ unsigned wcnt[8];

    bins[tid] = 0u; bins[tid + 512] = 0u;
    __syncthreads();

    float z = 0.f, u = 0.f, Ruv = 0.f, Rzv = 0.f, Sz = 0.f;
    for (int it = 0; it < 10; ++it){
        float Rv = Ruv - rho*(Rzv - Rwi);
        float b  = wi + Rv;
        float grad = W2i + rho*(z - b) + u + 2.f*lam*(Sz - 1.f);
        float zn = z - mu*grad;
        zn = (act && zn > 0.f) ? zn : 0.f;
        unsigned bits = __float_as_uint(zn);

        // radix select: 1 barrier/pass; per-pass private bin buffer; redundant per-wave scan
        unsigned prefix = 0, need = KSEL;
#pragma unroll
        for (int pass = 3; pass >= 0; --pass){
            int sh = pass*8;
            unsigned* bp = bins + ((3 - pass) << 8);
            bool av = (pass == 3) || ((bits >> (sh + 8)) == (prefix >> (sh + 8)));
            if (av) atomicAdd(&bp[(bits >> sh) & 255u], 1u);
            __syncthreads();
            int base = 255 - 4*lane;
            uint4 bq = *(const uint4*)&bp[base - 3];
            unsigned b3 = bq.x, b2 = bq.y, b1 = bq.z, b0 = bq.w;   // b0 = bp[base] (highest)
            unsigned csum = b0 + b1 + b2 + b3;
            unsigned incl = csum;
#pragma unroll
            for (int d = 1; d < 64; d <<= 1){ unsigned t = __shfl_up(incl, d); if (lane >= d) incl += t; }
            unsigned excl = incl - csum;
            bool hit = (excl < need) && (need <= incl);
            unsigned long long hm = __ballot(hit);
            int hl = __ffsll((long long)hm) - 1;
            unsigned c0 = excl + b0, c1 = c0 + b1, c2 = c1 + b2;
            int byte; unsigned above;
            if      (need <= c0){ byte = base;   above = excl; }
            else if (need <= c1){ byte = base-1; above = c0; }
            else if (need <= c2){ byte = base-2; above = c1; }
            else                { byte = base-3; above = c2; }
            byte  = __shfl(byte, hl);
            above = (unsigned)__shfl((int)above, hl);
            prefix |= ((unsigned)byte) << sh;
            need -= above;
        }
        z = (act && bits >= prefix) ? zn : 0.f;

        // Sz + support list
        bool flag = z > 0.f;
        unsigned long long mb = __ballot(flag);
        float v = z;
#pragma unroll
        for (int d = 1; d < 64; d <<= 1) v += __shfl_xor(v, d);
        if (lane == 0){ warr[wid] = v; wcnt[wid] = (unsigned)__popcll(mb); }
        __syncthreads();
        Sz = ((warr[0]+warr[1])+(warr[2]+warr[3])) + ((warr[4]+warr[5])+(warr[6]+warr[7]));

        if (it < 9){
            unsigned off = 0;
#pragma unroll
            for (int w2 = 0; w2 < 8; ++w2) if (w2 < wid) off += wcnt[w2];
            off += (unsigned)__popcll(mb & ((1ull << lane) - 1ull));
            int cnt = 0;
#pragma unroll
            for (int w2 = 0; w2 < 8; ++w2) cnt += (int)wcnt[w2];
            if (flag){ spair[off] = make_float2(__int_as_float(tid), z); }
            if (tid >= cnt && tid < 64){ spair[tid] = make_float2(__int_as_float(0), 0.f); }  // exact pad
            bins[tid] = 0u; bins[tid + 512] = 0u;   // re-zero for next iteration
            __syncthreads();

            // one ds_read_b64/thread; (idx,weight) broadcast via readlane imm -> SGPR
            float2 pp = spair[lane];
            const float* Rb = ws + WS_R;
            // phase 1: issue all 56 loads (SGPR row base + coalesced tid offset)
            float rvv[56];
#pragma unroll
            for (int s = 0; s < 56; ++s){
                int j = __float_as_int(rdl(pp.x, s));
                rvv[s] = Rb[(size_t)j*NDIM + ti];
            }
            // phase 2: accumulate with SGPR weights, 4 chains
            float a0=0.f, a1=0.f, a2=0.f, a3=0.f;
#pragma unroll
            for (int s = 0; s < 56; s += 4){
                a0 = fmaf(rvv[s+0], rdl(pp.y, s+0), a0);
                a1 = fmaf(rvv[s+1], rdl(pp.y, s+1), a1);
                a2 = fmaf(rvv[s+2], rdl(pp.y, s+2), a2);
                a3 = fmaf(rvv[s+3], rdl(pp.y, s+3), a3);
            }
            float acc = (a0+a1) + (a2+a3);
            float Rbv = Rwi + sc*Rv;                // R@b = Rw + (alpha/N)*Rv   (P^2 = P)
            u   += rho*(z - b);
            Ruv += rho*(acc - Rbv);
            Rzv  = acc;
        }
    }
    if (act) out[tid] = z / (Sz + 1e-8f);
}

extern "C" void kernel_launch(void* const* d_in, const int* in_sizes, int n_in,
                              void* d_out, int out_size, void* d_ws, size_t ws_size,
                              hipStream_t stream) {
    const float* x     = (const float*)d_in[0];
    const float* qt    = (const float*)d_in[1];
    const float* wv    = (const float*)d_in[2];
    // d_in[3] = b1 (unused by forward math)
    const float* alpha = (const float*)d_in[4];
    const float* lamda = (const float*)d_in[5];
    const float* rho   = (const float*)d_in[6];
    const float* mu    = (const float*)d_in[7];
    const float* lw    = (const float*)d_in[8];
    const float* lb    = (const float*)d_in[9];
    float* out = (float*)d_out;
    float* ws  = (float*)d_ws;

    k_gram_colsum<<<513, 512, 0, stream>>>(qt, x, wv, ws);
    k_cg_xbar    <<<177, 512, 0, stream>>>(qt, ws);
    k_w2_r       <<<590, 256, 0, stream>>>(qt, lw, lb, alpha, ws);
    k_iter       <<<1,   512, 0, stream>>>(wv, alpha, lamda, rho, mu, ws, out);
}

// Round 9
// 83.668 us; speedup vs baseline: 1.2625x; 1.1861x over previous
//
#include <hip/hip_runtime.h>

// Problem constants
#define NDIM 471
#define MD   128
#define TD   16384
#define KSEL 50
#define CGIT 12
#define WN   472            // W column count: 471 qt columns + 1 extra RHS (t1 = Q w)

// ws float-offset layout
#define WS_PART   0                 // [256][471] column-sum partials
#define WS_G      120832            // [128][128] Gram
#define WS_T1     137216            // [128]  t1 = Q w
#define WS_W      137472            // [128][472] W = Ginv @ [Q | t1] (via CG)
#define WS_XBAR   197888            // [471]
#define WS_W2     198400            // [471]
#define WS_RW     198912            // [471]  Rw = R @ w
#define WS_R      199424            // [471][471] R = (alpha/N) Q^T Ginv Q

// SGPR broadcast: readlane with compile-time lane index -> v_readlane_b32 s,v,imm
static __device__ __forceinline__ float rdl(float v, int lane){
    return __int_as_float(__builtin_amdgcn_readlane(__float_as_int(v), lane));
}

// ---- Kernel 1: blocks 0..255 Gram; 256..511 colsum partials; 512 t1 = Q w ----
__global__ __launch_bounds__(512) void k_gram_colsum(const float* __restrict__ qt,
                                                     const float* __restrict__ x,
                                                     const float* __restrict__ wv,
                                                     float* __restrict__ ws){
    int lane = threadIdx.x & 63, wid = threadIdx.x >> 6;
    if (blockIdx.x < 256){
        float* G = ws + WS_G;
        int gw = blockIdx.x * 8 + wid;          // 0..2047 waves
        int i = gw >> 4, jb = gw & 15;
        float qi[8];
#pragma unroll
        for (int s = 0; s < 8; ++s){ int idx = lane + 64*s; qi[s] = (idx < NDIM) ? qt[i*NDIM + idx] : 0.f; }
#pragma unroll
        for (int t = 0; t < 8; ++t){
            int j = jb + 16*t;
            float acc = 0.f;
#pragma unroll
            for (int s = 0; s < 8; ++s){
                int idx = lane + 64*s;
                float qj = (idx < NDIM) ? qt[j*NDIM + idx] : 0.f;
                acc = fmaf(qi[s], qj, acc);
            }
#pragma unroll
            for (int d = 1; d < 64; d <<= 1) acc += __shfl_xor(acc, d);
            if (lane == 0) G[i*MD + j] = acc;
        }
    } else if (blockIdx.x < 512){
        int cb = blockIdx.x - 256;              // 0..255, rows cb*64..+64
        int col = threadIdx.x;
        if (col < NDIM){
            const float* xp = x + (size_t)cb*64*NDIM + col;
            float acc = 0.f;
#pragma unroll 4
            for (int r = 0; r < 64; ++r) acc += xp[(size_t)r*NDIM];
            ws[WS_PART + cb*NDIM + col] = acc;
        }
    } else {
        // t1[m] = sum_idx qt[m][idx] * w[idx]
        for (int m = wid; m < MD; m += 8){
            float acc = 0.f;
#pragma unroll
            for (int s = 0; s < 8; ++s){
                int idx = lane + 64*s;
                if (idx < NDIM) acc = fmaf(qt[m*NDIM + idx], wv[idx], acc);
            }
#pragma unroll
            for (int d = 1; d < 64; d <<= 1) acc += __shfl_xor(acc, d);
            if (lane == 0) ws[WS_T1 + m] = acc;
        }
    }
}

// ---- Kernel 2: blocks 0..235 CG (2 cols/block, 256 thr, split-K named scalars);
//      blocks 236..294 xbar finalize.
// R8 lesson: per-iter cost was NEVER G-refetch; it's barrier width x VALU contention.
// 256 thr: 4 waves/barrier (was 8), 1 wave/SIMD (VALU issue halves), 236 CUs busy.
#define G_LD(n) float4 t##n = *(const float4*)(Gp + 4*(n)); \
                float Ga##n = t##n.x, Gb##n = t##n.y, Gc##n = t##n.z, Gd##n = t##n.w;
#define G_DOT(n) pa = fmaf(Ga##n, rdl(rch.x, 2*(n)),   pa); \
                 pb = fmaf(Gb##n, rdl(rch.y, 2*(n)),   pb); \
                 pa = fmaf(Gc##n, rdl(rch.x, 2*(n)+1), pa); \
                 pb = fmaf(Gd##n, rdl(rch.y, 2*(n)+1), pb);

__global__ __launch_bounds__(256, 1) void k_cg_xbar(const float* __restrict__ qt, float* __restrict__ ws){
    int tid = threadIdx.x, lane = tid & 63, wid = tid >> 6;
    if (blockIdx.x < 236){
        __shared__ __align__(16) float rl[2][128];       // r vector per RHS column
        __shared__ float part[2][2][128];                // [seg][c][row] partial dots
        __shared__ float red2[4][2];
        int row = tid & 127, seg = tid >> 7;             // seg in {0,1}, uniform per wave-pair
        int c   = seg;                                   // state role shares the split
        int col = blockIdx.x*2 + c;                      // 0..471 (col 471 = t1 RHS)
        // G slice: G[row][seg*64 .. seg*64+63] in 64 NAMED scalars (true VGPRs)
        const float* Gp = ws + WS_G + row*MD + seg*64;
        G_LD(0) G_LD(1) G_LD(2)  G_LD(3)  G_LD(4)  G_LD(5)  G_LD(6)  G_LD(7)
        G_LD(8) G_LD(9) G_LD(10) G_LD(11) G_LD(12) G_LD(13) G_LD(14) G_LD(15)
        float bvv = (col < NDIM) ? qt[row*NDIM + col] : ws[WS_T1 + row];
        float xv = 0.f, rv = bvv, pv = 0.f, sv = 0.f, gam = 1.f, alf = 1.f;
        rl[c][row] = rv;
        for (int it = 0; it < CGIT; ++it){
            __syncthreads();                             // A: rl visible
            // partial dots for both columns over this thread's 64-wide k-slice
#pragma unroll
            for (int cc = 0; cc < 2; ++cc){
                float2 rch = *(const float2*)&rl[cc][seg*64 + 2*(lane & 31)];
                float pa = 0.f, pb = 0.f;
                G_DOT(0) G_DOT(1) G_DOT(2)  G_DOT(3)  G_DOT(4)  G_DOT(5)  G_DOT(6)  G_DOT(7)
                G_DOT(8) G_DOT(9) G_DOT(10) G_DOT(11) G_DOT(12) G_DOT(13) G_DOT(14) G_DOT(15)
                part[seg][cc][row] = pa + pb;
            }
            __syncthreads();                             // B: part visible
            float y = part[0][c][row] + part[1][c][row];
            // fused dots: gamma' = (r,r), delta = (Gr, r)
            float t0 = rv*rv, t1 = y*rv;
#pragma unroll
            for (int d = 1; d < 64; d <<= 1){ t0 += __shfl_xor(t0, d); t1 += __shfl_xor(t1, d); }
            if (lane == 0){ red2[wid][0] = t0; red2[wid][1] = t1; }
            __syncthreads();                             // C: red2 visible
            float gp = red2[2*c][0] + red2[2*c+1][0];
            float dl = red2[2*c][1] + red2[2*c+1][1];
            float bet, anew;
            if (it == 0){ bet = 0.f; anew = gp / fmaxf(dl, 1e-30f); }
            else { bet = gp / fmaxf(gam, 1e-30f); anew = gp / fmaxf(dl - bet*gp/alf, 1e-30f); }
            pv = fmaf(bet, pv, rv);
            sv = fmaf(bet, sv, y);
            xv = fmaf(anew, pv, xv);
            rv = fmaf(-anew, sv, rv);
            gam = gp; alf = anew;
            rl[c][row] = rv;
        }
        ws[WS_W + row*WN + col] = xv;
    } else {
        // xbar finalize: 8 columns per block, 256 partial rows, 256 threads
        __shared__ float part[4][8];
        int b2 = blockIdx.x - 236;              // 0..58
        int cl = tid & 7, seg = tid >> 3;       // seg 0..31
        int col = b2*8 + cl;
        float acc = 0.f;
        if (col < NDIM){
#pragma unroll
            for (int q = 0; q < 8; ++q) acc += ws[WS_PART + (seg*8 + q)*NDIM + col];
        }
        acc += __shfl_xor(acc, 8);
        acc += __shfl_xor(acc, 16);
        acc += __shfl_xor(acc, 32);
        if (lane < 8) part[wid][lane] = acc;    // lane<8 => cl==lane
        __syncthreads();
        if (tid < 8){
            float t = ((part[0][tid] + part[1][tid]) + (part[2][tid] + part[3][tid]));
            int c2 = b2*8 + tid;
            if (c2 < NDIM) ws[WS_XBAR + c2] = t * (1.0f / TD);
        }
    }
}

// ---- Kernel 3: blocks 0..117 W2; 118..588 R rows; 589 Rw = sc*Q^T t2 ----
__global__ __launch_bounds__(256) void k_w2_r(const float* __restrict__ qt, const float* __restrict__ lw,
                                              const float* __restrict__ lb, const float* __restrict__ alpha,
                                              float* __restrict__ ws){
    if (blockIdx.x < 118){
        int lane = threadIdx.x & 63, wid = threadIdx.x >> 6;
        int i = blockIdx.x*4 + wid;
        if (i < NDIM){
            float acc = 0.f;
#pragma unroll
            for (int s = 0; s < 8; ++s){
                int idx = lane + 64*s;
                if (idx < NDIM) acc = fmaf(lw[(size_t)i*NDIM + idx], ws[WS_XBAR + idx], acc);
            }
#pragma unroll
            for (int d = 1; d < 64; d <<= 1) acc += __shfl_xor(acc, d);
            if (lane == 0) ws[WS_W2 + i] = acc + lb[i];
        }
    } else if (blockIdx.x < 589){
        int i = blockIdx.x - 118;           // 0..470 : row i of R
        __shared__ __align__(16) float qc[MD];
        int tid = threadIdx.x, lane = tid & 63;
        if (tid < MD) qc[tid] = qt[tid*NDIM + i];
        __syncthreads();
        float4 qv = ((const float4*)qc)[lane & 31];
        float sc = alpha[0] / (float)NDIM;
        const float* Wp = ws + WS_W;
        int j0 = tid;
        int j1 = (tid + 256 < NDIM) ? tid + 256 : (NDIM - 1);   // clamp (guarded store)
        float a0=0.f, a1=0.f, a2=0.f, a3=0.f;
        float b0=0.f, b1=0.f, b2=0.f, b3=0.f;
#pragma unroll 8
        for (int c = 0; c < 32; ++c){
            float p0 = rdl(qv.x, c), p1 = rdl(qv.y, c), p2 = rdl(qv.z, c), p3 = rdl(qv.w, c);
            const float* W0 = Wp + (4*c+0)*WN;
            const float* W1 = Wp + (4*c+1)*WN;
            const float* W2 = Wp + (4*c+2)*WN;
            const float* W3 = Wp + (4*c+3)*WN;
            a0 = fmaf(p0, W0[j0], a0); b0 = fmaf(p0, W0[j1], b0);
            a1 = fmaf(p1, W1[j0], a1); b1 = fmaf(p1, W1[j1], b1);
            a2 = fmaf(p2, W2[j0], a2); b2 = fmaf(p2, W2[j1], b2);
            a3 = fmaf(p3, W3[j0], a3); b3 = fmaf(p3, W3[j1], b3);
        }
        if (j0 < NDIM) ws[WS_R + (size_t)i*NDIM + j0] = sc * ((a0+a1) + (a2+a3));
        if (tid + 256 < NDIM) ws[WS_R + (size_t)i*NDIM + tid + 256] = sc * ((b0+b1) + (b2+b3));
    } else {
        // Rw_i = sc * sum_k qt[k][i] * t2[k],  t2 = W[:,471] = Ginv (Q w)
        __shared__ float t2l[MD];
        int tid = threadIdx.x;
        if (tid < MD) t2l[tid] = ws[WS_W + tid*WN + 471];
        __syncthreads();
        float sc = alpha[0] / (float)NDIM;
        for (int i = tid; i < NDIM; i += 256){
            float a0=0.f, a1=0.f, a2=0.f, a3=0.f;
#pragma unroll
            for (int k = 0; k < MD; k += 4){
                a0 = fmaf(qt[(k+0)*NDIM + i], t2l[k+0], a0);
                a1 = fmaf(qt[(k+1)*NDIM + i], t2l[k+1], a1);
                a2 = fmaf(qt[(k+2)*NDIM + i], t2l[k+2], a2);
                a3 = fmaf(qt[(k+3)*NDIM + i], t2l[k+3], a3);
            }
            ws[WS_RW + i] = sc * ((a0+a1) + (a2+a3));
        }
    }
}

// ---- Kernel 4: the 10-iteration solver (single block; prefetched matvec) ----
__global__ __launch_bounds__(512, 2) void k_iter(const float* __restrict__ wv,
                                              const float* __restrict__ alpha, const float* __restrict__ lamda,
                                              const float* __restrict__ rho_p, const float* __restrict__ mu_p,
                                              const float* __restrict__ ws, float* __restrict__ out){
    int tid = threadIdx.x, lane = tid & 63, wid = tid >> 6;
    bool act = tid < NDIM;
    int ti = act ? tid : 0;                      // clamped index for always-valid loads
    float rho = rho_p[0], mu = mu_p[0], lam = lamda[0];
    float sc  = alpha[0] / (float)NDIM;
    float wi  = act ? wv[tid]         : 0.f;
    float W2i = act ? ws[WS_W2 + tid] : 0.f;
    float Rwi = act ? ws[WS_RW + tid] : 0.f;

    __shared__ __align__(16) unsigned bins[1024];   // 4 buffers x 256 bins
    __shared__ __align__(8) float2 spair[64];       // packed (idx_bits, weight) support list
    __shared__ float warr[8];
    __shared__ unsigned wcnt[8];

    bins[tid] = 0u; bins[tid + 512] = 0u;
    __syncthreads();

    float z = 0.f, u = 0.f, Ruv = 0.f, Rzv = 0.f, Sz = 0.f;
    for (int it = 0; it < 10; ++it){
        float Rv = Ruv - rho*(Rzv - Rwi);
        float b  = wi + Rv;
        float grad = W2i + rho*(z - b) + u + 2.f*lam*(Sz - 1.f);
        float zn = z - mu*grad;
        zn = (act && zn > 0.f) ? zn : 0.f;
        unsigned bits = __float_as_uint(zn);

        // radix select: 1 barrier/pass; per-pass private bin buffer; redundant per-wave scan
        unsigned prefix = 0, need = KSEL;
#pragma unroll
        for (int pass = 3; pass >= 0; --pass){
            int sh = pass*8;
            unsigned* bp = bins + ((3 - pass) << 8);
            bool av = (pass == 3) || ((bits >> (sh + 8)) == (prefix >> (sh + 8)));
            if (av) atomicAdd(&bp[(bits >> sh) & 255u], 1u);
            __syncthreads();
            int base = 255 - 4*lane;
            uint4 bq = *(const uint4*)&bp[base - 3];
            unsigned b3 = bq.x, b2 = bq.y, b1 = bq.z, b0 = bq.w;   // b0 = bp[base] (highest)
            unsigned csum = b0 + b1 + b2 + b3;
            unsigned incl = csum;
#pragma unroll
            for (int d = 1; d < 64; d <<= 1){ unsigned t = __shfl_up(incl, d); if (lane >= d) incl += t; }
            unsigned excl = incl - csum;
            bool hit = (excl < need) && (need <= incl);
            unsigned long long hm = __ballot(hit);
            int hl = __ffsll((long long)hm) - 1;
            unsigned c0 = excl + b0, c1 = c0 + b1, c2 = c1 + b2;
            int byte; unsigned above;
            if      (need <= c0){ byte = base;   above = excl; }
            else if (need <= c1){ byte = base-1; above = c0; }
            else if (need <= c2){ byte = base-2; above = c1; }
            else                { byte = base-3; above = c2; }
            byte  = __shfl(byte, hl);
            above = (unsigned)__shfl((int)above, hl);
            prefix |= ((unsigned)byte) << sh;
            need -= above;
        }
        z = (act && bits >= prefix) ? zn : 0.f;

        // Sz + support list
        bool flag = z > 0.f;
        unsigned long long mb = __ballot(flag);
        float v = z;
#pragma unroll
        for (int d = 1; d < 64; d <<= 1) v += __shfl_xor(v, d);
        if (lane == 0){ warr[wid] = v; wcnt[wid] = (unsigned)__popcll(mb); }
        __syncthreads();
        Sz = ((warr[0]+warr[1])+(warr[2]+warr[3])) + ((warr[4]+warr[5])+(warr[6]+warr[7]));

        if (it < 9){
            unsigned off = 0;
#pragma unroll
            for (int w2 = 0; w2 < 8; ++w2) if (w2 < wid) off += wcnt[w2];
            off += (unsigned)__popcll(mb & ((1ull << lane) - 1ull));
            int cnt = 0;
#pragma unroll
            for (int w2 = 0; w2 < 8; ++w2) cnt += (int)wcnt[w2];
            if (flag){ spair[off] = make_float2(__int_as_float(tid), z); }
            if (tid >= cnt && tid < 64){ spair[tid] = make_float2(__int_as_float(0), 0.f); }  // exact pad
            bins[tid] = 0u; bins[tid + 512] = 0u;   // re-zero for next iteration
            __syncthreads();

            // one ds_read_b64/thread; (idx,weight) broadcast via readlane imm -> SGPR
            float2 pp = spair[lane];
            const float* Rb = ws + WS_R;
            // phase 1: issue all 56 loads (SGPR row base + coalesced tid offset)
            float rvv[56];
#pragma unroll
            for (int s = 0; s < 56; ++s){
                int j = __float_as_int(rdl(pp.x, s));
                rvv[s] = Rb[(size_t)j*NDIM + ti];
            }
            // phase 2: accumulate with SGPR weights, 4 chains
            float a0=0.f, a1=0.f, a2=0.f, a3=0.f;
#pragma unroll
            for (int s = 0; s < 56; s += 4){
                a0 = fmaf(rvv[s+0], rdl(pp.y, s+0), a0);
                a1 = fmaf(rvv[s+1], rdl(pp.y, s+1), a1);
                a2 = fmaf(rvv[s+2], rdl(pp.y, s+2), a2);
                a3 = fmaf(rvv[s+3], rdl(pp.y, s+3), a3);
            }
            float acc = (a0+a1) + (a2+a3);
            float Rbv = Rwi + sc*Rv;                // R@b = Rw + (alpha/N)*Rv   (P^2 = P)
            u   += rho*(z - b);
            Ruv += rho*(acc - Rbv);
            Rzv  = acc;
        }
    }
    if (act) out[tid] = z / (Sz + 1e-8f);
}

extern "C" void kernel_launch(void* const* d_in, const int* in_sizes, int n_in,
                              void* d_out, int out_size, void* d_ws, size_t ws_size,
                              hipStream_t stream) {
    const float* x     = (const float*)d_in[0];
    const float* qt    = (const float*)d_in[1];
    const float* wv    = (const float*)d_in[2];
    // d_in[3] = b1 (unused by forward math)
    const float* alpha = (const float*)d_in[4];
    const float* lamda = (const float*)d_in[5];
    const float* rho   = (const float*)d_in[6];
    const float* mu    = (const float*)d_in[7];
    const float* lw    = (const float*)d_in[8];
    const float* lb    = (const float*)d_in[9];
    float* out = (float*)d_out;
    float* ws  = (float*)d_ws;

    k_gram_colsum<<<513, 512, 0, stream>>>(qt, x, wv, ws);
    k_cg_xbar    <<<295, 256, 0, stream>>>(qt, ws);
    k_w2_r       <<<590, 256, 0, stream>>>(qt, lw, lb, alpha, ws);
    k_iter       <<<1,   512, 0, stream>>>(wv, alpha, lamda, rho, mu, ws, out);
}

// Round 10
// 83.609 us; speedup vs baseline: 1.2634x; 1.0007x over previous
//
#include <hip/hip_runtime.h>

// Problem constants
#define NDIM 471
#define MD   128
#define TD   16384
#define KSEL 50
#define CGIT 12
#define WN   472            // W column count: 471 qt columns + 1 extra RHS (t1 = Q w)

// ws float-offset layout
#define WS_PART   0                 // [256][471] column-sum partials
#define WS_G      120832            // [128][128] Gram
#define WS_T1     137216            // [128]  t1 = Q w
#define WS_W      137472            // [128][472] W = Ginv @ [Q | t1] (via CG)
#define WS_XBAR   197888            // [471]
#define WS_W2     198400            // [471]
#define WS_RW     198912            // [471]  Rw = R @ w
#define WS_R      199424            // [471][471] R = (alpha/N) Q^T Ginv Q

// SGPR broadcast: readlane with compile-time lane index -> v_readlane_b32 s,v,imm
static __device__ __forceinline__ float rdl(float v, int lane){
    return __int_as_float(__builtin_amdgcn_readlane(__float_as_int(v), lane));
}

// ---- Kernel 1: blocks 0..255 Gram; 256..511 colsum partials; 512 t1 = Q w ----
__global__ __launch_bounds__(512) void k_gram_colsum(const float* __restrict__ qt,
                                                     const float* __restrict__ x,
                                                     const float* __restrict__ wv,
                                                     float* __restrict__ ws){
    int lane = threadIdx.x & 63, wid = threadIdx.x >> 6;
    if (blockIdx.x < 256){
        float* G = ws + WS_G;
        int gw = blockIdx.x * 8 + wid;          // 0..2047 waves
        int i = gw >> 4, jb = gw & 15;
        float qi[8];
#pragma unroll
        for (int s = 0; s < 8; ++s){ int idx = lane + 64*s; qi[s] = (idx < NDIM) ? qt[i*NDIM + idx] : 0.f; }
#pragma unroll
        for (int t = 0; t < 8; ++t){
            int j = jb + 16*t;
            float acc = 0.f;
#pragma unroll
            for (int s = 0; s < 8; ++s){
                int idx = lane + 64*s;
                float qj = (idx < NDIM) ? qt[j*NDIM + idx] : 0.f;
                acc = fmaf(qi[s], qj, acc);
            }
#pragma unroll
            for (int d = 1; d < 64; d <<= 1) acc += __shfl_xor(acc, d);
            if (lane == 0) G[i*MD + j] = acc;
        }
    } else if (blockIdx.x < 512){
        int cb = blockIdx.x - 256;              // 0..255, rows cb*64..+64
        int col = threadIdx.x;
        if (col < NDIM){
            const float* xp = x + (size_t)cb*64*NDIM + col;
            float acc = 0.f;
#pragma unroll 4
            for (int r = 0; r < 64; ++r) acc += xp[(size_t)r*NDIM];
            ws[WS_PART + cb*NDIM + col] = acc;
        }
    } else {
        // t1[m] = sum_idx qt[m][idx] * w[idx]
        for (int m = wid; m < MD; m += 8){
            float acc = 0.f;
#pragma unroll
            for (int s = 0; s < 8; ++s){
                int idx = lane + 64*s;
                if (idx < NDIM) acc = fmaf(qt[m*NDIM + idx], wv[idx], acc);
            }
#pragma unroll
            for (int d = 1; d < 64; d <<= 1) acc += __shfl_xor(acc, d);
            if (lane == 0) ws[WS_T1 + m] = acc;
        }
    }
}

// ---- Kernel 2: blocks 0..235 CG (2 cols/block, 256 thr, split-K named scalars);
//      blocks 236..294 xbar finalize.
// R8 lesson: per-iter cost was NEVER G-refetch; it's barrier width x VALU contention.
// 256 thr: 4 waves/barrier (was 8), 1 wave/SIMD (VALU issue halves), 236 CUs busy.
#define G_LD(n) float4 t##n = *(const float4*)(Gp + 4*(n)); \
                float Ga##n = t##n.x, Gb##n = t##n.y, Gc##n = t##n.z, Gd##n = t##n.w;
#define G_DOT(n) pa = fmaf(Ga##n, rdl(rch.x, 2*(n)),   pa); \
                 pb = fmaf(Gb##n, rdl(rch.y, 2*(n)),   pb); \
                 pa = fmaf(Gc##n, rdl(rch.x, 2*(n)+1), pa); \
                 pb = fmaf(Gd##n, rdl(rch.y, 2*(n)+1), pb);

__global__ __launch_bounds__(256, 1) void k_cg_xbar(const float* __restrict__ qt, float* __restrict__ ws){
    int tid = threadIdx.x, lane = tid & 63, wid = tid >> 6;
    if (blockIdx.x < 236){
        __shared__ __align__(16) float rl[2][128];       // r vector per RHS column
        __shared__ float part[2][2][128];                // [seg][c][row] partial dots
        __shared__ float red2[4][2];
        int row = tid & 127, seg = tid >> 7;             // seg in {0,1}, uniform per wave-pair
        int c   = seg;                                   // state role shares the split
        int col = blockIdx.x*2 + c;                      // 0..471 (col 471 = t1 RHS)
        // G slice: G[row][seg*64 .. seg*64+63] in 64 NAMED scalars (true VGPRs)
        const float* Gp = ws + WS_G + row*MD + seg*64;
        G_LD(0) G_LD(1) G_LD(2)  G_LD(3)  G_LD(4)  G_LD(5)  G_LD(6)  G_LD(7)
        G_LD(8) G_LD(9) G_LD(10) G_LD(11) G_LD(12) G_LD(13) G_LD(14) G_LD(15)
        float bvv = (col < NDIM) ? qt[row*NDIM + col] : ws[WS_T1 + row];
        float xv = 0.f, rv = bvv, pv = 0.f, sv = 0.f, gam = 1.f, alf = 1.f;
        rl[c][row] = rv;
        for (int it = 0; it < CGIT; ++it){
            __syncthreads();                             // A: rl visible
            // partial dots for both columns over this thread's 64-wide k-slice
#pragma unroll
            for (int cc = 0; cc < 2; ++cc){
                float2 rch = *(const float2*)&rl[cc][seg*64 + 2*(lane & 31)];
                float pa = 0.f, pb = 0.f;
                G_DOT(0) G_DOT(1) G_DOT(2)  G_DOT(3)  G_DOT(4)  G_DOT(5)  G_DOT(6)  G_DOT(7)
                G_DOT(8) G_DOT(9) G_DOT(10) G_DOT(11) G_DOT(12) G_DOT(13) G_DOT(14) G_DOT(15)
                part[seg][cc][row] = pa + pb;
            }
            __syncthreads();                             // B: part visible
            float y = part[0][c][row] + part[1][c][row];
            // fused dots: gamma' = (r,r), delta = (Gr, r)
            float t0 = rv*rv, t1 = y*rv;
#pragma unroll
            for (int d = 1; d < 64; d <<= 1){ t0 += __shfl_xor(t0, d); t1 += __shfl_xor(t1, d); }
            if (lane == 0){ red2[wid][0] = t0; red2[wid][1] = t1; }
            __syncthreads();                             // C: red2 visible
            float gp = red2[2*c][0] + red2[2*c+1][0];
            float dl = red2[2*c][1] + red2[2*c+1][1];
            float bet, anew;
            if (it == 0){ bet = 0.f; anew = gp / fmaxf(dl, 1e-30f); }
            else { bet = gp / fmaxf(gam, 1e-30f); anew = gp / fmaxf(dl - bet*gp/alf, 1e-30f); }
            pv = fmaf(bet, pv, rv);
            sv = fmaf(bet, sv, y);
            xv = fmaf(anew, pv, xv);
            rv = fmaf(-anew, sv, rv);
            gam = gp; alf = anew;
            rl[c][row] = rv;
        }
        ws[WS_W + row*WN + col] = xv;
    } else {
        // xbar finalize: 8 columns per block, 256 partial rows, 256 threads
        __shared__ float part[4][8];
        int b2 = blockIdx.x - 236;              // 0..58
        int cl = tid & 7, seg = tid >> 3;       // seg 0..31
        int col = b2*8 + cl;
        float acc = 0.f;
        if (col < NDIM){
#pragma unroll
            for (int q = 0; q < 8; ++q) acc += ws[WS_PART + (seg*8 + q)*NDIM + col];
        }
        acc += __shfl_xor(acc, 8);
        acc += __shfl_xor(acc, 16);
        acc += __shfl_xor(acc, 32);
        if (lane < 8) part[wid][lane] = acc;    // lane<8 => cl==lane
        __syncthreads();
        if (tid < 8){
            float t = ((part[0][tid] + part[1][tid]) + (part[2][tid] + part[3][tid]));
            int c2 = b2*8 + tid;
            if (c2 < NDIM) ws[WS_XBAR + c2] = t * (1.0f / TD);
        }
    }
}

// ---- Kernel 3: blocks 0..117 W2; 118..588 R rows; 589 Rw = sc*Q^T t2 ----
__global__ __launch_bounds__(256) void k_w2_r(const float* __restrict__ qt, const float* __restrict__ lw,
                                              const float* __restrict__ lb, const float* __restrict__ alpha,
                                              float* __restrict__ ws){
    if (blockIdx.x < 118){
        int lane = threadIdx.x & 63, wid = threadIdx.x >> 6;
        int i = blockIdx.x*4 + wid;
        if (i < NDIM){
            float acc = 0.f;
#pragma unroll
            for (int s = 0; s < 8; ++s){
                int idx = lane + 64*s;
                if (idx < NDIM) acc = fmaf(lw[(size_t)i*NDIM + idx], ws[WS_XBAR + idx], acc);
            }
#pragma unroll
            for (int d = 1; d < 64; d <<= 1) acc += __shfl_xor(acc, d);
            if (lane == 0) ws[WS_W2 + i] = acc + lb[i];
        }
    } else if (blockIdx.x < 589){
        int i = blockIdx.x - 118;           // 0..470 : row i of R
        __shared__ __align__(16) float qc[MD];
        int tid = threadIdx.x, lane = tid & 63;
        if (tid < MD) qc[tid] = qt[tid*NDIM + i];
        __syncthreads();
        float4 qv = ((const float4*)qc)[lane & 31];
        float sc = alpha[0] / (float)NDIM;
        const float* Wp = ws + WS_W;
        int j0 = tid;
        int j1 = (tid + 256 < NDIM) ? tid + 256 : (NDIM - 1);   // clamp (guarded store)
        float a0=0.f, a1=0.f, a2=0.f, a3=0.f;
        float b0=0.f, b1=0.f, b2=0.f, b3=0.f;
#pragma unroll 8
        for (int c = 0; c < 32; ++c){
            float p0 = rdl(qv.x, c), p1 = rdl(qv.y, c), p2 = rdl(qv.z, c), p3 = rdl(qv.w, c);
            const float* W0 = Wp + (4*c+0)*WN;
            const float* W1 = Wp + (4*c+1)*WN;
            const float* W2 = Wp + (4*c+2)*WN;
            const float* W3 = Wp + (4*c+3)*WN;
            a0 = fmaf(p0, W0[j0], a0); b0 = fmaf(p0, W0[j1], b0);
            a1 = fmaf(p1, W1[j0], a1); b1 = fmaf(p1, W1[j1], b1);
            a2 = fmaf(p2, W2[j0], a2); b2 = fmaf(p2, W2[j1], b2);
            a3 = fmaf(p3, W3[j0], a3); b3 = fmaf(p3, W3[j1], b3);
        }
        if (j0 < NDIM) ws[WS_R + (size_t)i*NDIM + j0] = sc * ((a0+a1) + (a2+a3));
        if (tid + 256 < NDIM) ws[WS_R + (size_t)i*NDIM + tid + 256] = sc * ((b0+b1) + (b2+b3));
    } else {
        // Rw_i = sc * sum_k qt[k][i] * t2[k],  t2 = W[:,471] = Ginv (Q w)
        __shared__ float t2l[MD];
        int tid = threadIdx.x;
        if (tid < MD) t2l[tid] = ws[WS_W + tid*WN + 471];
        __syncthreads();
        float sc = alpha[0] / (float)NDIM;
        for (int i = tid; i < NDIM; i += 256){
            float a0=0.f, a1=0.f, a2=0.f, a3=0.f;
#pragma unroll
            for (int k = 0; k < MD; k += 4){
                a0 = fmaf(qt[(k+0)*NDIM + i], t2l[k+0], a0);
                a1 = fmaf(qt[(k+1)*NDIM + i], t2l[k+1], a1);
                a2 = fmaf(qt[(k+2)*NDIM + i], t2l[k+2], a2);
                a3 = fmaf(qt[(k+3)*NDIM + i], t2l[k+3], a3);
            }
            ws[WS_RW + i] = sc * ((a0+a1) + (a2+a3));
        }
    }
}

// ---- Kernel 4: the 10-iteration solver (single block; prefetched matvec) ----
__global__ __launch_bounds__(512, 2) void k_iter(const float* __restrict__ wv,
                                              const float* __restrict__ alpha, const float* __restrict__ lamda,
                                              const float* __restrict__ rho_p, const float* __restrict__ mu_p,
                                              const float* __restrict__ ws, float* __restrict__ out){
    int tid = threadIdx.x, lane = tid & 63, wid = tid >> 6;
    bool act = tid < NDIM;
    int ti = act ? tid : 0;                      // clamped index for always-valid loads
    float rho = rho_p[0], mu = mu_p[0], lam = lamda[0];
    float sc  = alpha[0] / (float)NDIM;
    float wi  = act ? wv[tid]         : 0.f;
    float W2i = act ? ws[WS_W2 + tid] : 0.f;
    float Rwi = act ? ws[WS_RW + tid] : 0.f;

    __shared__ __align__(16) unsigned bins[1024];   // 4 buffers x 256 bins
    __shared__ __align__(8) float2 spair[64];       // packed (idx_bits, weight) support list
    __shared__ float warr[8];
    __shared__ unsigned wcnt[8];

    bins[tid] = 0u; bins[tid + 512] = 0u;
    __syncthreads();

    float z = 0.f, u = 0.f, Ruv = 0.f, Rzv = 0.f, Sz = 0.f;
    for (int it = 0; it < 10; ++it){
        float Rv = Ruv - rho*(Rzv - Rwi);
        float b  = wi + Rv;
        float grad = W2i + rho*(z - b) + u + 2.f*lam*(Sz - 1.f);
        float zn = z - mu*grad;
        zn = (act && zn > 0.f) ? zn : 0.f;
        unsigned bits = __float_as_uint(zn);

        // radix select: 1 barrier/pass; per-pass private bin buffer; redundant per-wave scan
        unsigned prefix = 0, need = KSEL;
#pragma unroll
        for (int pass = 3; pass >= 0; --pass){
            int sh = pass*8;
            unsigned* bp = bins + ((3 - pass) << 8);
            bool av = (pass == 3) || ((bits >> (sh + 8)) == (prefix >> (sh + 8)));
            if (av) atomicAdd(&bp[(bits >> sh) & 255u], 1u);
            __syncthreads();
            int base = 255 - 4*lane;
            uint4 bq = *(const uint4*)&bp[base - 3];
            unsigned b3 = bq.x, b2 = bq.y, b1 = bq.z, b0 = bq.w;   // b0 = bp[base] (highest)
            unsigned csum = b0 + b1 + b2 + b3;
            unsigned incl = csum;
#pragma unroll
            for (int d = 1; d < 64; d <<= 1){ unsigned t = __shfl_up(incl, d); if (lane >= d) incl += t; }
            unsigned excl = incl - csum;
            bool hit = (excl < need) && (need <= incl);
            unsigned long long hm = __ballot(hit);
            int hl = __ffsll((long long)hm) - 1;
            unsigned c0 = excl + b0, c1 = c0 + b1, c2 = c1 + b2;
            int byte; unsigned above;
            if      (need <= c0){ byte = base;   above = excl; }
            else if (need <= c1){ byte = base-1; above = c0; }
            else if (need <= c2){ byte = base-2; above = c1; }
            else                { byte = base-3; above = c2; }
            byte  = __shfl(byte, hl);
            above = (unsigned)__shfl((int)above, hl);
            prefix |= ((unsigned)byte) << sh;
            need -= above;
        }
        z = (act && bits >= prefix) ? zn : 0.f;

        // Sz + support list
        bool flag = z > 0.f;
        unsigned long long mb = __ballot(flag);
        float v = z;
#pragma unroll
        for (int d = 1; d < 64; d <<= 1) v += __shfl_xor(v, d);
        if (lane == 0){ warr[wid] = v; wcnt[wid] = (unsigned)__popcll(mb); }
        __syncthreads();
        Sz = ((warr[0]+warr[1])+(warr[2]+warr[3])) + ((warr[4]+warr[5])+(warr[6]+warr[7]));

        if (it < 9){
            unsigned off = 0;
#pragma unroll
            for (int w2 = 0; w2 < 8; ++w2) if (w2 < wid) off += wcnt[w2];
            off += (unsigned)__popcll(mb & ((1ull << lane) - 1ull));
            int cnt = 0;
#pragma unroll
            for (int w2 = 0; w2 < 8; ++w2) cnt += (int)wcnt[w2];
            if (flag){ spair[off] = make_float2(__int_as_float(tid), z); }
            if (tid >= cnt && tid < 64){ spair[tid] = make_float2(__int_as_float(0), 0.f); }  // exact pad
            bins[tid] = 0u; bins[tid + 512] = 0u;   // re-zero for next iteration
            __syncthreads();

            // one ds_read_b64/thread; (idx,weight) broadcast via readlane imm -> SGPR
            float2 pp = spair[lane];
            const float* Rb = ws + WS_R;
            // phase 1: issue all 56 loads (SGPR row base + coalesced tid offset)
            float rvv[56];
#pragma unroll
            for (int s = 0; s < 56; ++s){
                int j = __float_as_int(rdl(pp.x, s));
                rvv[s] = Rb[(size_t)j*NDIM + ti];
            }
            // phase 2: accumulate with SGPR weights, 4 chains
            float a0=0.f, a1=0.f, a2=0.f, a3=0.f;
#pragma unroll
            for (int s = 0; s < 56; s += 4){
                a0 = fmaf(rvv[s+0], rdl(pp.y, s+0), a0);
                a1 = fmaf(rvv[s+1], rdl(pp.y, s+1), a1);
                a2 = fmaf(rvv[s+2], rdl(pp.y, s+2), a2);
                a3 = fmaf(rvv[s+3], rdl(pp.y, s+3), a3);
            }
            float acc = (a0+a1) + (a2+a3);
            float Rbv = Rwi + sc*Rv;                // R@b = Rw + (alpha/N)*Rv   (P^2 = P)
            u   += rho*(z - b);
            Ruv += rho*(acc - Rbv);
            Rzv  = acc;
        }
    }
    if (act) out[tid] = z / (Sz + 1e-8f);
}

extern "C" void kernel_launch(void* const* d_in, const int* in_sizes, int n_in,
                              void* d_out, int out_size, void* d_ws, size_t ws_size,
                              hipStream_t stream) {
    const float* x     = (const float*)d_in[0];
    const float* qt    = (const float*)d_in[1];
    const float* wv    = (const float*)d_in[2];
    // d_in[3] = b1 (unused by forward math)
    const float* alpha = (const float*)d_in[4];
    const float* lamda = (const float*)d_in[5];
    const float* rho   = (const float*)d_in[6];
    const float* mu    = (const float*)d_in[7];
    const float* lw    = (const float*)d_in[8];
    const float* lb    = (const float*)d_in[9];
    float* out = (float*)d_out;
    float* ws  = (float*)d_ws;

    k_gram_colsum<<<513, 512, 0, stream>>>(qt, x, wv, ws);
    k_cg_xbar    <<<295, 256, 0, stream>>>(qt, ws);
    k_w2_r       <<<590, 256, 0, stream>>>(qt, lw, lb, alpha, ws);
    k_iter       <<<1,   512, 0, stream>>>(wv, alpha, lamda, rho, mu, ws, out);
}

// Round 11
// 68.595 us; speedup vs baseline: 1.5399x; 1.2189x over previous
//
#include <hip/hip_runtime.h>

// Problem constants
#define NDIM 471
#define MD   128
#define TD   16384
#define KSEL 50
#define CGIT 8

// ws float-offset layout
#define WS_PART   0                 // [256][471] column-sum partials
#define WS_G      120832            // [128][128] Gram
#define WS_T1     137216            // [128]  t1 = Q w
#define WS_XBAR   197888            // [471]
#define WS_W2     198400            // [471]
#define WS_RW     198912            // [471]  Rw = R @ w
#define WS_R      199424            // [471][471] R = (alpha/N) Q^T Ginv Q  (row col = R[col][:], symmetric)

// SGPR broadcast: readlane with compile-time lane index -> v_readlane_b32 s,v,imm
static __device__ __forceinline__ float rdl(float v, int lane){
    return __int_as_float(__builtin_amdgcn_readlane(__float_as_int(v), lane));
}

// ---- Kernel 1: blocks 0..255 Gram; 256..511 colsum partials; 512 t1 = Q w ----
__global__ __launch_bounds__(512) void k_gram_colsum(const float* __restrict__ qt,
                                                     const float* __restrict__ x,
                                                     const float* __restrict__ wv,
                                                     float* __restrict__ ws){
    int lane = threadIdx.x & 63, wid = threadIdx.x >> 6;
    if (blockIdx.x < 256){
        float* G = ws + WS_G;
        int gw = blockIdx.x * 8 + wid;          // 0..2047 waves
        int i = gw >> 4, jb = gw & 15;
        float qi[8];
#pragma unroll
        for (int s = 0; s < 8; ++s){ int idx = lane + 64*s; qi[s] = (idx < NDIM) ? qt[i*NDIM + idx] : 0.f; }
#pragma unroll
        for (int t = 0; t < 8; ++t){
            int j = jb + 16*t;
            float acc = 0.f;
#pragma unroll
            for (int s = 0; s < 8; ++s){
                int idx = lane + 64*s;
                float qj = (idx < NDIM) ? qt[j*NDIM + idx] : 0.f;
                acc = fmaf(qi[s], qj, acc);
            }
#pragma unroll
            for (int d = 1; d < 64; d <<= 1) acc += __shfl_xor(acc, d);
            if (lane == 0) G[i*MD + j] = acc;
        }
    } else if (blockIdx.x < 512){
        int cb = blockIdx.x - 256;              // 0..255, rows cb*64..+64
        int col = threadIdx.x;
        if (col < NDIM){
            const float* xp = x + (size_t)cb*64*NDIM + col;
            float acc = 0.f;
#pragma unroll 4
            for (int r = 0; r < 64; ++r) acc += xp[(size_t)r*NDIM];
            ws[WS_PART + cb*NDIM + col] = acc;
        }
    } else {
        // t1[m] = sum_idx qt[m][idx] * w[idx]
        for (int m = wid; m < MD; m += 8){
            float acc = 0.f;
#pragma unroll
            for (int s = 0; s < 8; ++s){
                int idx = lane + 64*s;
                if (idx < NDIM) acc = fmaf(qt[m*NDIM + idx], wv[idx], acc);
            }
#pragma unroll
            for (int d = 1; d < 64; d <<= 1) acc += __shfl_xor(acc, d);
            if (lane == 0) ws[WS_T1 + m] = acc;
        }
    }
}

// ---- Kernel 2: blocks 0..235 CG (2 cols/block) + FUSED R/RW epilogue; 236..294 xbar ----
// Block b solves W cols {2b, 2b+1} (col 471 = t1 RHS), then computes R rows 2b,2b+1
// in-place (R symmetric: R[col][i] = sc * sum_k qt[k][i] * W[k][col]); col 471 -> RW.
// W itself is never stored.
#define G_LD(n) float4 t##n = *(const float4*)(Gp + 4*(n)); \
                float Ga##n = t##n.x, Gb##n = t##n.y, Gc##n = t##n.z, Gd##n = t##n.w;
#define G_DOT(n) pa = fmaf(Ga##n, rdl(rch.x, 2*(n)),   pa); \
                 pb = fmaf(Gb##n, rdl(rch.y, 2*(n)),   pb); \
                 pa = fmaf(Gc##n, rdl(rch.x, 2*(n)+1), pa); \
                 pb = fmaf(Gd##n, rdl(rch.y, 2*(n)+1), pb);

__global__ __launch_bounds__(256, 1) void k_cg_xbar(const float* __restrict__ qt,
                                                    const float* __restrict__ alpha,
                                                    float* __restrict__ ws){
    int tid = threadIdx.x, lane = tid & 63, wid = tid >> 6;
    if (blockIdx.x < 236){
        __shared__ __align__(16) float rl[2][128];       // r vector per RHS column
        __shared__ float part[2][2][128];                // [seg][c][row] partial dots
        __shared__ float red2[4][2];
        int row = tid & 127, seg = tid >> 7;             // seg in {0,1}
        int c   = seg;
        int col = blockIdx.x*2 + c;                      // 0..471 (col 471 = t1 RHS)
        const float* Gp = ws + WS_G + row*MD + seg*64;   // 64 named scalars (true VGPRs)
        G_LD(0) G_LD(1) G_LD(2)  G_LD(3)  G_LD(4)  G_LD(5)  G_LD(6)  G_LD(7)
        G_LD(8) G_LD(9) G_LD(10) G_LD(11) G_LD(12) G_LD(13) G_LD(14) G_LD(15)
        float bvv = (col < NDIM) ? qt[row*NDIM + col] : ws[WS_T1 + row];
        float xv = 0.f, rv = bvv, pv = 0.f, sv = 0.f, gam = 1.f, alf = 1.f;
        rl[c][row] = rv;
        for (int it = 0; it < CGIT; ++it){
            __syncthreads();                             // A: rl visible
#pragma unroll
            for (int cc = 0; cc < 2; ++cc){
                float2 rch = *(const float2*)&rl[cc][seg*64 + 2*(lane & 31)];
                float pa = 0.f, pb = 0.f;
                G_DOT(0) G_DOT(1) G_DOT(2)  G_DOT(3)  G_DOT(4)  G_DOT(5)  G_DOT(6)  G_DOT(7)
                G_DOT(8) G_DOT(9) G_DOT(10) G_DOT(11) G_DOT(12) G_DOT(13) G_DOT(14) G_DOT(15)
                part[seg][cc][row] = pa + pb;
            }
            __syncthreads();                             // B: part visible
            float y = part[0][c][row] + part[1][c][row];
            float t0 = rv*rv, t1 = y*rv;                 // gamma'=(r,r), delta=(Gr,r)
#pragma unroll
            for (int d = 1; d < 64; d <<= 1){ t0 += __shfl_xor(t0, d); t1 += __shfl_xor(t1, d); }
            if (lane == 0){ red2[wid][0] = t0; red2[wid][1] = t1; }
            __syncthreads();                             // C: red2 visible
            float gp = red2[2*c][0] + red2[2*c+1][0];
            float dl = red2[2*c][1] + red2[2*c+1][1];
            float bet, anew;
            if (it == 0){ bet = 0.f; anew = gp / fmaxf(dl, 1e-30f); }
            else { bet = gp / fmaxf(gam, 1e-30f); anew = gp / fmaxf(dl - bet*gp/alf, 1e-30f); }
            pv = fmaf(bet, pv, rv);
            sv = fmaf(bet, sv, y);
            xv = fmaf(anew, pv, xv);
            rv = fmaf(-anew, sv, rv);
            gam = gp; alf = anew;
            rl[c][row] = rv;
        }
        // ---- fused epilogue: R rows 2b,2b+1 (or RW for col 471) ----
        rl[c][row] = xv;                                 // own slot; no race pre-barrier
        __syncthreads();
        float sc = alpha[0] / (float)NDIM;
        float2 wc0 = ((const float2*)&rl[0][0])[lane];   // rl[0][2*lane], rl[0][2*lane+1]
        float2 wc1 = ((const float2*)&rl[1][0])[lane];
        int i0 = tid;
        int i1 = (tid + 256 < NDIM) ? tid + 256 : (NDIM - 1);   // clamp (guarded store)
        float a0=0.f, a1=0.f, b0=0.f, b1=0.f;
#pragma unroll
        for (int l = 0; l < 64; ++l){
            float w0a = rdl(wc0.x, l), w0b = rdl(wc0.y, l);
            float w1a = rdl(wc1.x, l), w1b = rdl(wc1.y, l);
            float qa0 = qt[(2*l+0)*NDIM + i0], qa1 = qt[(2*l+0)*NDIM + i1];
            float qb0 = qt[(2*l+1)*NDIM + i0], qb1 = qt[(2*l+1)*NDIM + i1];
            a0 = fmaf(qa0, w0a, a0); a0 = fmaf(qb0, w0b, a0);
            a1 = fmaf(qa1, w0a, a1); a1 = fmaf(qb1, w0b, a1);
            b0 = fmaf(qa0, w1a, b0); b0 = fmaf(qb0, w1b, b0);
            b1 = fmaf(qa1, w1a, b1); b1 = fmaf(qb1, w1b, b1);
        }
        int col0 = blockIdx.x*2, col1 = col0 + 1;
        ws[WS_R + (size_t)col0*NDIM + i0] = sc*a0;
        if (tid + 256 < NDIM) ws[WS_R + (size_t)col0*NDIM + tid+256] = sc*a1;
        if (col1 < NDIM){
            ws[WS_R + (size_t)col1*NDIM + i0] = sc*b0;
            if (tid + 256 < NDIM) ws[WS_R + (size_t)col1*NDIM + tid+256] = sc*b1;
        } else {                                         // col1 == 471 -> Rw
            ws[WS_RW + i0] = sc*b0;
            if (tid + 256 < NDIM) ws[WS_RW + tid+256] = sc*b1;
        }
    } else {
        // xbar finalize: 8 columns per block, 256 partial rows, 256 threads
        __shared__ float part[4][8];
        int b2 = blockIdx.x - 236;              // 0..58
        int cl = tid & 7, seg = tid >> 3;       // seg 0..31
        int col = b2*8 + cl;
        float acc = 0.f;
        if (col < NDIM){
#pragma unroll
            for (int q = 0; q < 8; ++q) acc += ws[WS_PART + (seg*8 + q)*NDIM + col];
        }
        acc += __shfl_xor(acc, 8);
        acc += __shfl_xor(acc, 16);
        acc += __shfl_xor(acc, 32);
        if (lane < 8) part[wid][lane] = acc;    // lane<8 => cl==lane
        __syncthreads();
        if (tid < 8){
            float t = ((part[0][tid] + part[1][tid]) + (part[2][tid] + part[3][tid]));
            int c2 = b2*8 + tid;
            if (c2 < NDIM) ws[WS_XBAR + c2] = t * (1.0f / TD);
        }
    }
}

// ---- Kernel 3: W2 = lw @ xbar + lb (118 blocks x 4 rows) ----
__global__ __launch_bounds__(256) void k_w2(const float* __restrict__ lw, const float* __restrict__ lb,
                                            float* __restrict__ ws){
    int lane = threadIdx.x & 63, wid = threadIdx.x >> 6;
    int i = blockIdx.x*4 + wid;
    if (i < NDIM){
        float acc = 0.f;
#pragma unroll
        for (int s = 0; s < 8; ++s){
            int idx = lane + 64*s;
            if (idx < NDIM) acc = fmaf(lw[(size_t)i*NDIM + idx], ws[WS_XBAR + idx], acc);
        }
#pragma unroll
        for (int d = 1; d < 64; d <<= 1) acc += __shfl_xor(acc, d);
        if (lane == 0) ws[WS_W2 + i] = acc + lb[i];
    }
}

// ---- Kernel 4: the 10-iteration solver (single block; early-exit radix select) ----
__global__ __launch_bounds__(512, 2) void k_iter(const float* __restrict__ wv,
                                              const float* __restrict__ alpha, const float* __restrict__ lamda,
                                              const float* __restrict__ rho_p, const float* __restrict__ mu_p,
                                              const float* __restrict__ ws, float* __restrict__ out){
    int tid = threadIdx.x, lane = tid & 63, wid = tid >> 6;
    bool act = tid < NDIM;
    int ti = act ? tid : 0;                      // clamped index for always-valid loads
    float rho = rho_p[0], mu = mu_p[0], lam = lamda[0];
    float sc  = alpha[0] / (float)NDIM;
    float wi  = act ? wv[tid]         : 0.f;
    float W2i = act ? ws[WS_W2 + tid] : 0.f;
    float Rwi = act ? ws[WS_RW + tid] : 0.f;

    __shared__ __align__(16) unsigned bins[1024];   // 4 buffers x 256 bins
    __shared__ __align__(8) float2 spair[64];       // packed (idx_bits, weight) support list
    __shared__ float warr[8];
    __shared__ unsigned wcnt[8];

    bins[tid] = 0u; bins[tid + 512] = 0u;
    __syncthreads();

    float z = 0.f, u = 0.f, Ruv = 0.f, Rzv = 0.f, Sz = 0.f;
    for (int it = 0; it < 10; ++it){
        float Rv = Ruv - rho*(Rzv - Rwi);
        float b  = wi + Rv;
        float grad = W2i + rho*(z - b) + u + 2.f*lam*(Sz - 1.f);
        float zn = z - mu*grad;
        zn = (act && zn > 0.f) ? zn : 0.f;
        unsigned bits = __float_as_uint(zn);

        // radix select with EARLY EXIT: when the chosen bin's count equals the
        // remaining need, tau is exact at this byte granularity -> skip lower passes.
        unsigned prefix = 0, need = KSEL;
#pragma unroll
        for (int pass = 3; pass >= 0; --pass){
            int sh = pass*8;
            unsigned* bp = bins + ((3 - pass) << 8);
            bool av = (pass == 3) || ((bits >> (sh + 8)) == (prefix >> (sh + 8)));
            if (av) atomicAdd(&bp[(bits >> sh) & 255u], 1u);
            __syncthreads();
            int base = 255 - 4*lane;
            uint4 bq = *(const uint4*)&bp[base - 3];
            unsigned b3 = bq.x, b2 = bq.y, b1 = bq.z, b0 = bq.w;   // b0 = bp[base] (highest)
            unsigned csum = b0 + b1 + b2 + b3;
            unsigned incl = csum;
#pragma unroll
            for (int d = 1; d < 64; d <<= 1){ unsigned t = __shfl_up(incl, d); if (lane >= d) incl += t; }
            unsigned excl = incl - csum;
            bool hit = (excl < need) && (need <= incl);
            unsigned long long hm = __ballot(hit);
            int hl = __ffsll((long long)hm) - 1;
            unsigned c0 = excl + b0, c1 = c0 + b1, c2 = c1 + b2;
            int byte; unsigned above, cntc;
            if      (need <= c0){ byte = base;   above = excl; cntc = b0; }
            else if (need <= c1){ byte = base-1; above = c0;   cntc = b1; }
            else if (need <= c2){ byte = base-2; above = c1;   cntc = b2; }
            else                { byte = base-3; above = c2;   cntc = b3; }
            byte  = __shfl(byte, hl);
            above = (unsigned)__shfl((int)above, hl);
            cntc  = (unsigned)__shfl((int)cntc, hl);
            prefix |= ((unsigned)byte) << sh;
            need -= above;
            if (cntc == need) break;              // boundary exact at this granularity
        }
        z = (act && bits >= prefix) ? zn : 0.f;

        // Sz + support list
        bool flag = z > 0.f;
        unsigned long long mb = __ballot(flag);
        float v = z;
#pragma unroll
        for (int d = 1; d < 64; d <<= 1) v += __shfl_xor(v, d);
        if (lane == 0){ warr[wid] = v; wcnt[wid] = (unsigned)__popcll(mb); }
        __syncthreads();
        Sz = ((warr[0]+warr[1])+(warr[2]+warr[3])) + ((warr[4]+warr[5])+(warr[6]+warr[7]));

        if (it < 9){
            unsigned off = 0;
#pragma unroll
            for (int w2 = 0; w2 < 8; ++w2) if (w2 < wid) off += wcnt[w2];
            off += (unsigned)__popcll(mb & ((1ull << lane) - 1ull));
            int cnt = 0;
#pragma unroll
            for (int w2 = 0; w2 < 8; ++w2) cnt += (int)wcnt[w2];
            if (flag){ spair[off] = make_float2(__int_as_float(tid), z); }
            if (tid >= cnt && tid < 64){ spair[tid] = make_float2(__int_as_float(0), 0.f); }  // exact pad
            bins[tid] = 0u; bins[tid + 512] = 0u;   // re-zero for next iteration
            __syncthreads();

            // one ds_read_b64/thread; (idx,weight) broadcast via readlane imm -> SGPR
            float2 pp = spair[lane];
            const float* Rb = ws + WS_R;
            float rvv[56];
#pragma unroll
            for (int s = 0; s < 56; ++s){
                int j = __float_as_int(rdl(pp.x, s));
                rvv[s] = Rb[(size_t)j*NDIM + ti];
            }
            float a0=0.f, a1=0.f, a2=0.f, a3=0.f;
#pragma unroll
            for (int s = 0; s < 56; s += 4){
                a0 = fmaf(rvv[s+0], rdl(pp.y, s+0), a0);
                a1 = fmaf(rvv[s+1], rdl(pp.y, s+1), a1);
                a2 = fmaf(rvv[s+2], rdl(pp.y, s+2), a2);
                a3 = fmaf(rvv[s+3], rdl(pp.y, s+3), a3);
            }
            float acc = (a0+a1) + (a2+a3);
            float Rbv = Rwi + sc*Rv;                // R@b = Rw + (alpha/N)*Rv   (P^2 = P)
            u   += rho*(z - b);
            Ruv += rho*(acc - Rbv);
            Rzv  = acc;
        }
    }
    if (act) out[tid] = z / (Sz + 1e-8f);
}

extern "C" void kernel_launch(void* const* d_in, const int* in_sizes, int n_in,
                              void* d_out, int out_size, void* d_ws, size_t ws_size,
                              hipStream_t stream) {
    const float* x     = (const float*)d_in[0];
    const float* qt    = (const float*)d_in[1];
    const float* wv    = (const float*)d_in[2];
    // d_in[3] = b1 (unused by forward math)
    const float* alpha = (const float*)d_in[4];
    const float* lamda = (const float*)d_in[5];
    const float* rho   = (const float*)d_in[6];
    const float* mu    = (const float*)d_in[7];
    const float* lw    = (const float*)d_in[8];
    const float* lb    = (const float*)d_in[9];
    float* out = (float*)d_out;
    float* ws  = (float*)d_ws;

    k_gram_colsum<<<513, 512, 0, stream>>>(qt, x, wv, ws);
    k_cg_xbar    <<<295, 256, 0, stream>>>(qt, alpha, ws);
    k_w2         <<<118, 256, 0, stream>>>(lw, lb, ws);
    k_iter       <<<1,   512, 0, stream>>>(wv, alpha, lamda, rho, mu, ws, out);
}